// Round 14
// baseline (249.602 us; speedup 1.0000x reference)
//
#include <hip/hip_runtime.h>

#define EPS_LN 1e-5f
#define EPS_BN 1e-5f

typedef float f4 __attribute__((ext_vector_type(4)));

__device__ __forceinline__ float lrelu(float v) { return v >= 0.f ? v : 0.2f * v; }

// half-pixel 16->64 axis map: src = 0.25*o - 0.375 = (2o-3)/8
__device__ __forceinline__ void axis16(int o, int& i0, int& i1, float& f) {
  int t = 2 * o - 3;
  int q = (t >= 0) ? (t >> 3) : -1;       // floor(t/8); t >= -3 so floor=-1
  f = (float)(t - 8 * q) * 0.125f;
  i0 = q < 0 ? 0 : q;
  i1 = q + 1 > 15 ? 15 : q + 1;
}

// ---------------------------------------------------------------------------
// Kernel A2: GAT1 (+ReLU) -> GAT2 -> LayerNorm + residual -> xlg (48x9).
// (byte-identical to R10/R11; measured ~20 us)
// ---------------------------------------------------------------------------
__global__ __launch_bounds__(512) void kA2(
    const float* __restrict__ obj, const int* __restrict__ eidx,
    const float* __restrict__ W1, const float* __restrict__ as1w,
    const float* __restrict__ ad1w, const float* __restrict__ b1,
    const float* __restrict__ W2, const float* __restrict__ as2w,
    const float* __restrict__ ad2w, const float* __restrict__ b2,
    const float* __restrict__ lng, const float* __restrict__ lnb,
    float* __restrict__ xlg)
{
  const int tid = threadIdx.x;
  __shared__ float xin[48][9];
  __shared__ float h1[48][32];
  __shared__ float a1s[48][4], a1d[48][4];
  __shared__ float m1[48][4], r1[48][4];
  __shared__ float w1[816][4];
  __shared__ float x2[48][32];
  __shared__ float h2s[48][9];
  __shared__ float a2s[48], a2d[48], m2[48], r2[48];
  __shared__ float w2[816];
  __shared__ float g2[48][9];
  __shared__ int esrc[816], etgt[816];
  __shared__ int es[816], et[816];
  __shared__ int chunkCnt[48][48];
  __shared__ int offs[49], colsum[48];

  for (int i = tid; i < 768; i += 512) { esrc[i] = eidx[i]; etgt[i] = eidx[768 + i]; }
  if (tid < 48) { esrc[768 + tid] = tid; etgt[768 + tid] = tid; }
  for (int i = tid; i < 432; i += 512) xin[i / 9][i % 9] = obj[i];
  for (int i = tid; i < 2304; i += 512) ((int*)chunkCnt)[i] = 0;
  __syncthreads();

  if (tid < 48) {
    const int c = tid;
    for (int j = 0; j < 17; ++j) chunkCnt[c][etgt[c * 17 + j]]++;
  }
  __syncthreads();
  if (tid < 48) {
    int s = 0;
    for (int c = 0; c < 48; ++c) s += chunkCnt[c][tid];
    colsum[tid] = s;
  }
  __syncthreads();
  if (tid == 0) { offs[0] = 0; for (int n = 0; n < 48; ++n) offs[n + 1] = offs[n] + colsum[n]; }
  __syncthreads();
  if (tid < 48) {
    int run = offs[tid];
    for (int c = 0; c < 48; ++c) { int v = chunkCnt[c][tid]; chunkCnt[c][tid] = run; run += v; }
  }
  __syncthreads();
  if (tid < 48) {
    const int c = tid;
    for (int j = 0; j < 17; ++j) {
      int e = c * 17 + j, n = etgt[e];
      int pos = chunkCnt[c][n]++;
      es[pos] = esrc[e]; et[pos] = n;
    }
  }

  for (int i = tid; i < 1536; i += 512) {
    int n = i >> 5, j = i & 31;
    float s = 0.f;
    for (int f = 0; f < 9; ++f) s += xin[n][f] * W1[f * 32 + j];
    h1[n][j] = s;
  }
  __syncthreads();

  for (int i = tid; i < 192; i += 512) {
    int n = i >> 2, h = i & 3;
    float ss = 0.f, sd = 0.f;
    for (int c = 0; c < 8; ++c) {
      float v = h1[n][h * 8 + c];
      ss += v * as1w[h * 8 + c];
      sd += v * ad1w[h * 8 + c];
    }
    a1s[n][h] = ss; a1d[n][h] = sd;
  }
  __syncthreads();

  for (int i = tid; i < 192; i += 512) {
    int n = i >> 2, h = i & 3;
    float ad = a1d[n][h];
    float mx = -1e30f;
    for (int p = offs[n]; p < offs[n + 1]; ++p)
      mx = fmaxf(mx, lrelu(a1s[es[p]][h] + ad));
    m1[n][h] = mx;
  }
  __syncthreads();

  for (int i = tid; i < 3264; i += 512) {
    int p = i >> 2, h = i & 3, n = et[p];
    w1[p][h] = expf(lrelu(a1s[es[p]][h] + a1d[n][h]) - m1[n][h]);
  }
  __syncthreads();

  for (int i = tid; i < 192; i += 512) {
    int n = i >> 2, h = i & 3;
    float s = 0.f;
    for (int p = offs[n]; p < offs[n + 1]; ++p) s += w1[p][h];
    r1[n][h] = 1.f / (s + 1e-16f);
  }
  __syncthreads();

  for (int i = tid; i < 1536; i += 512) {
    int n = i >> 5, j = i & 31, h = j >> 3;
    float acc = 0.f;
    for (int p = offs[n]; p < offs[n + 1]; ++p)
      acc += w1[p][h] * h1[es[p]][j];
    x2[n][j] = fmaxf(acc * r1[n][h] + b1[j], 0.f);
  }
  __syncthreads();

  for (int i = tid; i < 432; i += 512) {
    int n = i / 9, k = i % 9;
    float s = 0.f;
    for (int c = 0; c < 32; ++c) s += x2[n][c] * W2[c * 9 + k];
    h2s[n][k] = s;
  }
  __syncthreads();
  if (tid < 48) {
    float ss = 0.f, sd = 0.f;
    for (int k = 0; k < 9; ++k) { ss += h2s[tid][k] * as2w[k]; sd += h2s[tid][k] * ad2w[k]; }
    a2s[tid] = ss; a2d[tid] = sd;
  }
  __syncthreads();
  if (tid < 48) {
    float ad = a2d[tid];
    float mx = -1e30f;
    for (int p = offs[tid]; p < offs[tid + 1]; ++p)
      mx = fmaxf(mx, lrelu(a2s[es[p]] + ad));
    m2[tid] = mx;
  }
  __syncthreads();
  for (int i = tid; i < 816; i += 512) {
    int n = et[i];
    w2[i] = expf(lrelu(a2s[es[i]] + a2d[n]) - m2[n]);
  }
  __syncthreads();
  if (tid < 48) {
    float s = 0.f;
    for (int p = offs[tid]; p < offs[tid + 1]; ++p) s += w2[p];
    r2[tid] = 1.f / (s + 1e-16f);
  }
  __syncthreads();
  for (int i = tid; i < 432; i += 512) {
    int n = i / 9, k = i % 9;
    float acc = 0.f;
    for (int p = offs[n]; p < offs[n + 1]; ++p)
      acc += w2[p] * h2s[es[p]][k];
    g2[n][k] = acc * r2[n] + b2[k];
  }
  __syncthreads();

  if (tid < 48) {
    float mu = 0.f;
    for (int k = 0; k < 9; ++k) mu += g2[tid][k];
    mu *= (1.f / 9.f);
    float var = 0.f;
    for (int k = 0; k < 9; ++k) { float dd = g2[tid][k] - mu; var += dd * dd; }
    var *= (1.f / 9.f);
    float is = rsqrtf(var + EPS_LN);
    for (int k = 0; k < 9; ++k)
      xlg[tid * 9 + k] = lng[k] * (g2[tid][k] - mu) * is + lnb[k] + xin[tid][k];
  }
}

// ---------------------------------------------------------------------------
// Kernel BC: Linear(9->2048)+ReLU per block into LDS, then ConvT1 -> hct1.
// (byte-identical to R10)
// ---------------------------------------------------------------------------
__global__ __launch_bounds__(256) void kBC(
    const float* __restrict__ xlg, const float* __restrict__ linW,
    const float* __restrict__ linb, const float* __restrict__ w,
    const float* __restrict__ bias, float* __restrict__ outp)
{
  const int co = blockIdx.x, n = blockIdx.y, tid = threadIdx.x;
  __shared__ float xls[9];
  __shared__ float xs[2048];
  __shared__ float wsd[2048];
  if (tid < 9) xls[tid] = xlg[n * 9 + tid];
  for (int q = tid; q < 2048; q += 256) {
    int ci = q >> 6, t = q & 63;
    wsd[q] = w[ci * 1024 + co * 64 + t];
  }
  __syncthreads();
  for (int q = tid; q < 2048; q += 256) {
    float s = linb[q];
#pragma unroll
    for (int k = 0; k < 9; ++k) s += xls[k] * linW[k * 2048 + q];
    xs[q] = fmaxf(s, 0.f);
  }
  __syncthreads();

  const int od = tid >> 5, oh = (tid >> 2) & 7, owp = tid & 3;
  float acc0 = 0.f, acc1 = 0.f;
  const int kd0 = 1 - (od & 1), kh0 = 1 - (oh & 1);
#pragma unroll
  for (int kdi = 0; kdi < 2; ++kdi) {
    int kd = kd0 + 2 * kdi;
    int id = (od + 1 - kd) >> 1;
    if ((unsigned)id >= 4u) continue;
#pragma unroll
    for (int khi = 0; khi < 2; ++khi) {
      int kh = kh0 + 2 * khi;
      int ih = (oh + 1 - kh) >> 1;
      if ((unsigned)ih >= 4u) continue;
      for (int ci = 0; ci < 32; ++ci) {
        const float* xr = &xs[ci * 64 + id * 16 + ih * 4];
        const float* wr = &wsd[ci * 64 + kd * 16 + kh * 4];
        float x0 = xr[owp];
        float xm1 = owp > 0 ? xr[owp - 1] : 0.f;
        float xp1 = owp < 3 ? xr[owp + 1] : 0.f;
        acc0 += x0 * wr[1];
        acc0 += xm1 * wr[3];
        acc1 += xp1 * wr[0];
        acc1 += x0 * wr[2];
      }
    }
  }
  const float bb = bias[co];
  float2 o;
  o.x = fmaxf(acc0 + bb, 0.f);
  o.y = fmaxf(acc1 + bb, 0.f);
  *(float2*)&outp[(n * 16 + co) * 512 + od * 64 + oh * 8 + 2 * owp] = o;
}

// ---------------------------------------------------------------------------
// Kernel D: ConvT2 -> h2 (48,9,16^3) + BN partial sums. (byte-identical)
// ---------------------------------------------------------------------------
__global__ __launch_bounds__(256) void kD(
    const float* __restrict__ x, const float* __restrict__ w,
    const float* __restrict__ bias, float* __restrict__ outp,
    float* __restrict__ psum, float* __restrict__ pssq)
{
  const int co = blockIdx.x, n = blockIdx.y, tid = threadIdx.x;
  __shared__ float xs[8192];
  __shared__ float wsd[1024];
  __shared__ float rs[256], rq[256];
  {
    const float4* src = (const float4*)(x + (size_t)n * 8192);
    float4* dst = (float4*)xs;
    for (int q = tid; q < 2048; q += 256) dst[q] = src[q];
  }
  for (int q = tid; q < 1024; q += 256) {
    int ci = q >> 6, t = q & 63;
    wsd[q] = w[(ci * 9 + co) * 64 + t];
  }
  __syncthreads();
  const int od = tid >> 4, oh = tid & 15;
  float acc[16];
#pragma unroll
  for (int i = 0; i < 16; ++i) acc[i] = 0.f;
  const int kd0 = 1 - (od & 1), kh0 = 1 - (oh & 1);
#pragma unroll
  for (int kdi = 0; kdi < 2; ++kdi) {
    int kd = kd0 + 2 * kdi;
    int id = (od + 1 - kd) >> 1;
    if ((unsigned)id >= 8u) continue;
#pragma unroll
    for (int khi = 0; khi < 2; ++khi) {
      int kh = kh0 + 2 * khi;
      int ih = (oh + 1 - kh) >> 1;
      if ((unsigned)ih >= 8u) continue;
      for (int ci = 0; ci < 16; ++ci) {
        const float* xr = &xs[ci * 512 + id * 64 + ih * 8];
        const float* wr = &wsd[ci * 64 + kd * 16 + kh * 4];
        float xv[8], wv[4];
#pragma unroll
        for (int t = 0; t < 8; ++t) xv[t] = xr[t];
#pragma unroll
        for (int t = 0; t < 4; ++t) wv[t] = wr[t];
#pragma unroll
        for (int ow = 0; ow < 16; ++ow) {
          const int kw0 = 1 - (ow & 1);
          const int iw0 = (ow + 1 - kw0) >> 1;
          if (iw0 < 8) acc[ow] += xv[iw0] * wv[kw0];
          if (iw0 - 1 >= 0) acc[ow] += xv[iw0 - 1] * wv[kw0 + 2];
        }
      }
    }
  }
  const float bb = bias[co];
  float s = 0.f, q = 0.f;
  float4* op = (float4*)(outp + (size_t)(n * 9 + co) * 4096 + od * 256 + oh * 16);
#pragma unroll
  for (int t = 0; t < 4; ++t) {
    float4 v;
    v.x = acc[4 * t] + bb; v.y = acc[4 * t + 1] + bb;
    v.z = acc[4 * t + 2] + bb; v.w = acc[4 * t + 3] + bb;
    op[t] = v;
    s += v.x + v.y + v.z + v.w;
    q += v.x * v.x + v.y * v.y + v.z * v.z + v.w * v.w;
  }
  rs[tid] = s; rq[tid] = q;
  __syncthreads();
  for (int off = 128; off > 0; off >>= 1) {
    if (tid < off) { rs[tid] += rs[tid + off]; rq[tid] += rq[tid + off]; }
    __syncthreads();
  }
  if (tid == 0) { psum[co * 48 + n] = rs[0]; pssq[co * 48 + n] = rq[0]; }
}

// ---------------------------------------------------------------------------
// Kernel F6: separable trilinear + BN affine + residual add.
// NEW vs kF3/kF4: 256 threads, 4-od slab -> LDS ~19.3 KB (plane [4][64][16]
// = 16 KB + hs 3 z-slices = 3 KB) and lower VGPR -> 4+ blocks/CU instead of
// 2. More co-resident independent blocks keep the memory pipe busy while any
// one block sits in its (halved) plane-build phase. Math identical.
// ---------------------------------------------------------------------------
__global__ __launch_bounds__(256) void kF6(
    const float* __restrict__ vol, const float* __restrict__ h2,
    const float* __restrict__ psum, const float* __restrict__ pssq,
    const float* __restrict__ bng, const float* __restrict__ bnb,
    const float* __restrict__ scp, float* __restrict__ outp)
{
  const int slab = blockIdx.x, c = blockIdx.y, n = blockIdx.z, tid = threadIdx.x;
  __shared__ float hs[768];      // 3 z-slices of h2[n][c] : [3][16][16]
  __shared__ float plane[4096];  // zy-interp plane [4][64][16]
  __shared__ float abS[2];

  const int od_base = slab * 4;
  const size_t gbase = ((size_t)(n * 9 + c) * 64 + od_base) * 1024;  // f4 units
  const f4* v4 = (const f4*)vol;
  f4* o4 = (f4*)outp;

  // batch-0 vol loads first (8 f4): in flight across staging + plane build
  f4 vv0[8];
#pragma unroll
  for (int i = 0; i < 8; ++i) vv0[i] = v4[gbase + (size_t)(tid + i * 256)];

  // z-slice base: slices zb..zb+2 cover z in [slab-1, slab+1] clamped
  int zb = slab - 1;
  zb = zb < 0 ? 0 : (zb > 13 ? 13 : zb);
  if (tid < 192) {
    const f4* src = (const f4*)(h2 + (size_t)(n * 9 + c) * 4096) + zb * 64;
    ((f4*)hs)[tid] = src[tid];   // 192 f4 = 3 slices
  }
  if (tid < 64) {   // BN finalize: reduce 48 partials in wave 0
    float s = (tid < 48) ? psum[c * 48 + tid] : 0.f;
    float q = (tid < 48) ? pssq[c * 48 + tid] : 0.f;
#pragma unroll
    for (int off = 32; off > 0; off >>= 1) {
      s += __shfl_down(s, off);
      q += __shfl_down(q, off);
    }
    if (tid == 0) {
      float mean = s * (1.f / 196608.f);
      float var = q * (1.f / 196608.f) - mean * mean;
      float Aa = bng[c] * rsqrtf(var + EPS_BN);
      abS[0] = Aa;
      abS[1] = bnb[c] - Aa * mean;
    }
  }
  const float sc = scp[0];
  __syncthreads();

  // pass 1: zy plane (4096 elements, 16 iters)
#pragma unroll
  for (int j = 0; j < 16; ++j) {
    int e = tid + j * 256;
    int x = e & 15, oh = (e >> 4) & 63, od = e >> 10;
    int z0, z1, y0, y1; float fz, fy;
    axis16(od_base + od, z0, z1, fz);
    axis16(oh, y0, y1, fy);
    float w00 = (1.f - fz) * (1.f - fy), w01 = (1.f - fz) * fy;
    float w10 = fz * (1.f - fy), w11 = fz * fy;
    int bz0 = (z0 - zb) << 8, bz1 = (z1 - zb) << 8;
    int by0 = y0 << 4, by1 = y1 << 4;
    plane[e] = w00 * hs[bz0 + by0 + x] + w01 * hs[bz0 + by1 + x]
             + w10 * hs[bz1 + by0 + x] + w11 * hs[bz1 + by1 + x];
  }
  __syncthreads();

  // batch-1 vol loads (8 f4) in flight while batch 0 computes
  f4 vv1[8];
#pragma unroll
  for (int i = 0; i < 8; ++i) vv1[i] = v4[gbase + (size_t)(tid + (8 + i) * 256)];

  const float Aa = abS[0], Bb = abS[1];

#pragma unroll
  for (int i = 0; i < 8; ++i) {
    int u = tid + i * 256;
    int owq = u & 15, base = (u >> 4) << 4;
    int xa = owq ? owq - 1 : 0;
    int xc = owq < 15 ? owq + 1 : 15;
    float A = plane[base + xa], B = plane[base + owq], C = plane[base + xc];
    f4 oo;
    oo.x = vv0[i].x + sc * fmaf(Aa, A + 0.625f * (B - A), Bb);
    oo.y = vv0[i].y + sc * fmaf(Aa, A + 0.875f * (B - A), Bb);
    oo.z = vv0[i].z + sc * fmaf(Aa, B + 0.125f * (C - B), Bb);
    oo.w = vv0[i].w + sc * fmaf(Aa, B + 0.375f * (C - B), Bb);
    o4[gbase + (size_t)u] = oo;
  }
#pragma unroll
  for (int i = 0; i < 8; ++i) {
    int u = tid + (8 + i) * 256;
    int owq = u & 15, base = (u >> 4) << 4;
    int xa = owq ? owq - 1 : 0;
    int xc = owq < 15 ? owq + 1 : 15;
    float A = plane[base + xa], B = plane[base + owq], C = plane[base + xc];
    f4 oo;
    oo.x = vv1[i].x + sc * fmaf(Aa, A + 0.625f * (B - A), Bb);
    oo.y = vv1[i].y + sc * fmaf(Aa, A + 0.875f * (B - A), Bb);
    oo.z = vv1[i].z + sc * fmaf(Aa, B + 0.125f * (C - B), Bb);
    oo.w = vv1[i].w + sc * fmaf(Aa, B + 0.375f * (C - B), Bb);
    o4[gbase + (size_t)u] = oo;
  }
}

// ---------------------------------------------------------------------------
extern "C" void kernel_launch(void* const* d_in, const int* in_sizes, int n_in,
                              void* d_out, int out_size, void* d_ws, size_t ws_size,
                              hipStream_t stream) {
  (void)in_sizes; (void)n_in; (void)out_size; (void)ws_size;
  const float* obj  = (const float*)d_in[0];
  const int*   eidx = (const int*)d_in[1];
  const float* vol  = (const float*)d_in[2];
  const float* W1   = (const float*)d_in[3];
  const float* as1  = (const float*)d_in[4];
  const float* ad1  = (const float*)d_in[5];
  const float* b1   = (const float*)d_in[6];
  const float* W2   = (const float*)d_in[7];
  const float* as2  = (const float*)d_in[8];
  const float* ad2  = (const float*)d_in[9];
  const float* b2   = (const float*)d_in[10];
  const float* lng  = (const float*)d_in[11];
  const float* lnb  = (const float*)d_in[12];
  const float* scp  = (const float*)d_in[13];
  const float* linW = (const float*)d_in[14];
  const float* linb = (const float*)d_in[15];
  const float* ct1W = (const float*)d_in[16];
  const float* ct1b = (const float*)d_in[17];
  const float* ct2W = (const float*)d_in[18];
  const float* ct2b = (const float*)d_in[19];
  const float* bng  = (const float*)d_in[20];
  const float* bnb  = (const float*)d_in[21];

  float* ws   = (float*)d_ws;
  float* xlg  = ws;                  // 432 f
  float* hct1 = ws + 432;            // 393216 f
  float* h2   = ws + 393648;         // 1769472 f
  float* psum = ws + 2163120;        // 432 f
  float* pssq = ws + 2163552;        // 432 f  (~8.66 MB)

  float* out = (float*)d_out;

  kA2<<<1, 512, 0, stream>>>(obj, eidx, W1, as1, ad1, b1, W2, as2, ad2, b2,
                             lng, lnb, xlg);
  kBC<<<dim3(16, 48), 256, 0, stream>>>(xlg, linW, linb, ct1W, ct1b, hct1);
  kD<<<dim3(9, 48), 256, 0, stream>>>(hct1, ct2W, ct2b, h2, psum, pssq);
  kF6<<<dim3(16, 9, 48), 256, 0, stream>>>(vol, h2, psum, pssq, bng, bnb, scp, out);
}

// Round 15
// 226.947 us; speedup vs baseline: 1.0998x; 1.0998x over previous
//
#include <hip/hip_runtime.h>

#define EPS_LN 1e-5f
#define EPS_BN 1e-5f

typedef float f4 __attribute__((ext_vector_type(4)));

__device__ __forceinline__ float lrelu(float v) { return v >= 0.f ? v : 0.2f * v; }

// half-pixel 16->64 axis map: src = 0.25*o - 0.375 = (2o-3)/8
__device__ __forceinline__ void axis16(int o, int& i0, int& i1, float& f) {
  int t = 2 * o - 3;
  int q = (t >= 0) ? (t >> 3) : -1;       // floor(t/8); t >= -3 so floor=-1
  f = (float)(t - 8 * q) * 0.125f;
  i0 = q < 0 ? 0 : q;
  i1 = q + 1 > 15 ? 15 : q + 1;
}

// ---------------------------------------------------------------------------
// Kernel A2: GAT1 (+ReLU) -> GAT2 -> LayerNorm + residual -> xlg (48x9).
// (byte-identical to R10/R11; measured ~20 us)
// ---------------------------------------------------------------------------
__global__ __launch_bounds__(512) void kA2(
    const float* __restrict__ obj, const int* __restrict__ eidx,
    const float* __restrict__ W1, const float* __restrict__ as1w,
    const float* __restrict__ ad1w, const float* __restrict__ b1,
    const float* __restrict__ W2, const float* __restrict__ as2w,
    const float* __restrict__ ad2w, const float* __restrict__ b2,
    const float* __restrict__ lng, const float* __restrict__ lnb,
    float* __restrict__ xlg)
{
  const int tid = threadIdx.x;
  __shared__ float xin[48][9];
  __shared__ float h1[48][32];
  __shared__ float a1s[48][4], a1d[48][4];
  __shared__ float m1[48][4], r1[48][4];
  __shared__ float w1[816][4];
  __shared__ float x2[48][32];
  __shared__ float h2s[48][9];
  __shared__ float a2s[48], a2d[48], m2[48], r2[48];
  __shared__ float w2[816];
  __shared__ float g2[48][9];
  __shared__ int esrc[816], etgt[816];
  __shared__ int es[816], et[816];
  __shared__ int chunkCnt[48][48];
  __shared__ int offs[49], colsum[48];

  for (int i = tid; i < 768; i += 512) { esrc[i] = eidx[i]; etgt[i] = eidx[768 + i]; }
  if (tid < 48) { esrc[768 + tid] = tid; etgt[768 + tid] = tid; }
  for (int i = tid; i < 432; i += 512) xin[i / 9][i % 9] = obj[i];
  for (int i = tid; i < 2304; i += 512) ((int*)chunkCnt)[i] = 0;
  __syncthreads();

  if (tid < 48) {
    const int c = tid;
    for (int j = 0; j < 17; ++j) chunkCnt[c][etgt[c * 17 + j]]++;
  }
  __syncthreads();
  if (tid < 48) {
    int s = 0;
    for (int c = 0; c < 48; ++c) s += chunkCnt[c][tid];
    colsum[tid] = s;
  }
  __syncthreads();
  if (tid == 0) { offs[0] = 0; for (int n = 0; n < 48; ++n) offs[n + 1] = offs[n] + colsum[n]; }
  __syncthreads();
  if (tid < 48) {
    int run = offs[tid];
    for (int c = 0; c < 48; ++c) { int v = chunkCnt[c][tid]; chunkCnt[c][tid] = run; run += v; }
  }
  __syncthreads();
  if (tid < 48) {
    const int c = tid;
    for (int j = 0; j < 17; ++j) {
      int e = c * 17 + j, n = etgt[e];
      int pos = chunkCnt[c][n]++;
      es[pos] = esrc[e]; et[pos] = n;
    }
  }

  for (int i = tid; i < 1536; i += 512) {
    int n = i >> 5, j = i & 31;
    float s = 0.f;
    for (int f = 0; f < 9; ++f) s += xin[n][f] * W1[f * 32 + j];
    h1[n][j] = s;
  }
  __syncthreads();

  for (int i = tid; i < 192; i += 512) {
    int n = i >> 2, h = i & 3;
    float ss = 0.f, sd = 0.f;
    for (int c = 0; c < 8; ++c) {
      float v = h1[n][h * 8 + c];
      ss += v * as1w[h * 8 + c];
      sd += v * ad1w[h * 8 + c];
    }
    a1s[n][h] = ss; a1d[n][h] = sd;
  }
  __syncthreads();

  for (int i = tid; i < 192; i += 512) {
    int n = i >> 2, h = i & 3;
    float ad = a1d[n][h];
    float mx = -1e30f;
    for (int p = offs[n]; p < offs[n + 1]; ++p)
      mx = fmaxf(mx, lrelu(a1s[es[p]][h] + ad));
    m1[n][h] = mx;
  }
  __syncthreads();

  for (int i = tid; i < 3264; i += 512) {
    int p = i >> 2, h = i & 3, n = et[p];
    w1[p][h] = expf(lrelu(a1s[es[p]][h] + a1d[n][h]) - m1[n][h]);
  }
  __syncthreads();

  for (int i = tid; i < 192; i += 512) {
    int n = i >> 2, h = i & 3;
    float s = 0.f;
    for (int p = offs[n]; p < offs[n + 1]; ++p) s += w1[p][h];
    r1[n][h] = 1.f / (s + 1e-16f);
  }
  __syncthreads();

  for (int i = tid; i < 1536; i += 512) {
    int n = i >> 5, j = i & 31, h = j >> 3;
    float acc = 0.f;
    for (int p = offs[n]; p < offs[n + 1]; ++p)
      acc += w1[p][h] * h1[es[p]][j];
    x2[n][j] = fmaxf(acc * r1[n][h] + b1[j], 0.f);
  }
  __syncthreads();

  for (int i = tid; i < 432; i += 512) {
    int n = i / 9, k = i % 9;
    float s = 0.f;
    for (int c = 0; c < 32; ++c) s += x2[n][c] * W2[c * 9 + k];
    h2s[n][k] = s;
  }
  __syncthreads();
  if (tid < 48) {
    float ss = 0.f, sd = 0.f;
    for (int k = 0; k < 9; ++k) { ss += h2s[tid][k] * as2w[k]; sd += h2s[tid][k] * ad2w[k]; }
    a2s[tid] = ss; a2d[tid] = sd;
  }
  __syncthreads();
  if (tid < 48) {
    float ad = a2d[tid];
    float mx = -1e30f;
    for (int p = offs[tid]; p < offs[tid + 1]; ++p)
      mx = fmaxf(mx, lrelu(a2s[es[p]] + ad));
    m2[tid] = mx;
  }
  __syncthreads();
  for (int i = tid; i < 816; i += 512) {
    int n = et[i];
    w2[i] = expf(lrelu(a2s[es[i]] + a2d[n]) - m2[n]);
  }
  __syncthreads();
  if (tid < 48) {
    float s = 0.f;
    for (int p = offs[tid]; p < offs[tid + 1]; ++p) s += w2[p];
    r2[tid] = 1.f / (s + 1e-16f);
  }
  __syncthreads();
  for (int i = tid; i < 432; i += 512) {
    int n = i / 9, k = i % 9;
    float acc = 0.f;
    for (int p = offs[n]; p < offs[n + 1]; ++p)
      acc += w2[p] * h2s[es[p]][k];
    g2[n][k] = acc * r2[n] + b2[k];
  }
  __syncthreads();

  if (tid < 48) {
    float mu = 0.f;
    for (int k = 0; k < 9; ++k) mu += g2[tid][k];
    mu *= (1.f / 9.f);
    float var = 0.f;
    for (int k = 0; k < 9; ++k) { float dd = g2[tid][k] - mu; var += dd * dd; }
    var *= (1.f / 9.f);
    float is = rsqrtf(var + EPS_LN);
    for (int k = 0; k < 9; ++k)
      xlg[tid * 9 + k] = lng[k] * (g2[tid][k] - mu) * is + lnb[k] + xin[tid][k];
  }
}

// ---------------------------------------------------------------------------
// Kernel BC: Linear(9->2048)+ReLU per block into LDS, then ConvT1 -> hct1.
// (byte-identical to R10)
// ---------------------------------------------------------------------------
__global__ __launch_bounds__(256) void kBC(
    const float* __restrict__ xlg, const float* __restrict__ linW,
    const float* __restrict__ linb, const float* __restrict__ w,
    const float* __restrict__ bias, float* __restrict__ outp)
{
  const int co = blockIdx.x, n = blockIdx.y, tid = threadIdx.x;
  __shared__ float xls[9];
  __shared__ float xs[2048];
  __shared__ float wsd[2048];
  if (tid < 9) xls[tid] = xlg[n * 9 + tid];
  for (int q = tid; q < 2048; q += 256) {
    int ci = q >> 6, t = q & 63;
    wsd[q] = w[ci * 1024 + co * 64 + t];
  }
  __syncthreads();
  for (int q = tid; q < 2048; q += 256) {
    float s = linb[q];
#pragma unroll
    for (int k = 0; k < 9; ++k) s += xls[k] * linW[k * 2048 + q];
    xs[q] = fmaxf(s, 0.f);
  }
  __syncthreads();

  const int od = tid >> 5, oh = (tid >> 2) & 7, owp = tid & 3;
  float acc0 = 0.f, acc1 = 0.f;
  const int kd0 = 1 - (od & 1), kh0 = 1 - (oh & 1);
#pragma unroll
  for (int kdi = 0; kdi < 2; ++kdi) {
    int kd = kd0 + 2 * kdi;
    int id = (od + 1 - kd) >> 1;
    if ((unsigned)id >= 4u) continue;
#pragma unroll
    for (int khi = 0; khi < 2; ++khi) {
      int kh = kh0 + 2 * khi;
      int ih = (oh + 1 - kh) >> 1;
      if ((unsigned)ih >= 4u) continue;
      for (int ci = 0; ci < 32; ++ci) {
        const float* xr = &xs[ci * 64 + id * 16 + ih * 4];
        const float* wr = &wsd[ci * 64 + kd * 16 + kh * 4];
        float x0 = xr[owp];
        float xm1 = owp > 0 ? xr[owp - 1] : 0.f;
        float xp1 = owp < 3 ? xr[owp + 1] : 0.f;
        acc0 += x0 * wr[1];
        acc0 += xm1 * wr[3];
        acc1 += xp1 * wr[0];
        acc1 += x0 * wr[2];
      }
    }
  }
  const float bb = bias[co];
  float2 o;
  o.x = fmaxf(acc0 + bb, 0.f);
  o.y = fmaxf(acc1 + bb, 0.f);
  *(float2*)&outp[(n * 16 + co) * 512 + od * 64 + oh * 8 + 2 * owp] = o;
}

// ---------------------------------------------------------------------------
// Kernel D: ConvT2 -> h2 (48,9,16^3) + BN partial sums. (byte-identical)
// ---------------------------------------------------------------------------
__global__ __launch_bounds__(256) void kD(
    const float* __restrict__ x, const float* __restrict__ w,
    const float* __restrict__ bias, float* __restrict__ outp,
    float* __restrict__ psum, float* __restrict__ pssq)
{
  const int co = blockIdx.x, n = blockIdx.y, tid = threadIdx.x;
  __shared__ float xs[8192];
  __shared__ float wsd[1024];
  __shared__ float rs[256], rq[256];
  {
    const float4* src = (const float4*)(x + (size_t)n * 8192);
    float4* dst = (float4*)xs;
    for (int q = tid; q < 2048; q += 256) dst[q] = src[q];
  }
  for (int q = tid; q < 1024; q += 256) {
    int ci = q >> 6, t = q & 63;
    wsd[q] = w[(ci * 9 + co) * 64 + t];
  }
  __syncthreads();
  const int od = tid >> 4, oh = tid & 15;
  float acc[16];
#pragma unroll
  for (int i = 0; i < 16; ++i) acc[i] = 0.f;
  const int kd0 = 1 - (od & 1), kh0 = 1 - (oh & 1);
#pragma unroll
  for (int kdi = 0; kdi < 2; ++kdi) {
    int kd = kd0 + 2 * kdi;
    int id = (od + 1 - kd) >> 1;
    if ((unsigned)id >= 8u) continue;
#pragma unroll
    for (int khi = 0; khi < 2; ++khi) {
      int kh = kh0 + 2 * khi;
      int ih = (oh + 1 - kh) >> 1;
      if ((unsigned)ih >= 8u) continue;
      for (int ci = 0; ci < 16; ++ci) {
        const float* xr = &xs[ci * 512 + id * 64 + ih * 8];
        const float* wr = &wsd[ci * 64 + kd * 16 + kh * 4];
        float xv[8], wv[4];
#pragma unroll
        for (int t = 0; t < 8; ++t) xv[t] = xr[t];
#pragma unroll
        for (int t = 0; t < 4; ++t) wv[t] = wr[t];
#pragma unroll
        for (int ow = 0; ow < 16; ++ow) {
          const int kw0 = 1 - (ow & 1);
          const int iw0 = (ow + 1 - kw0) >> 1;
          if (iw0 < 8) acc[ow] += xv[iw0] * wv[kw0];
          if (iw0 - 1 >= 0) acc[ow] += xv[iw0 - 1] * wv[kw0 + 2];
        }
      }
    }
  }
  const float bb = bias[co];
  float s = 0.f, q = 0.f;
  float4* op = (float4*)(outp + (size_t)(n * 9 + co) * 4096 + od * 256 + oh * 16);
#pragma unroll
  for (int t = 0; t < 4; ++t) {
    float4 v;
    v.x = acc[4 * t] + bb; v.y = acc[4 * t + 1] + bb;
    v.z = acc[4 * t + 2] + bb; v.w = acc[4 * t + 3] + bb;
    op[t] = v;
    s += v.x + v.y + v.z + v.w;
    q += v.x * v.x + v.y * v.y + v.z * v.z + v.w * v.w;
  }
  rs[tid] = s; rq[tid] = q;
  __syncthreads();
  for (int off = 128; off > 0; off >>= 1) {
    if (tid < off) { rs[tid] += rs[tid + off]; rq[tid] += rq[tid + off]; }
    __syncthreads();
  }
  if (tid == 0) { psum[co * 48 + n] = rs[0]; pssq[co * 48 + n] = rq[0]; }
}

// ---------------------------------------------------------------------------
// Kernel E2: finalize BN affine A[c], B[c] so BN(v) = A*v + B.  (tiny)
// ---------------------------------------------------------------------------
__global__ __launch_bounds__(64) void kE2(
    const float* __restrict__ psum, const float* __restrict__ pssq,
    const float* __restrict__ bng, const float* __restrict__ bnb,
    float* __restrict__ AB)
{
  const int c = threadIdx.x;
  if (c >= 9) return;
  float s = 0.f, q = 0.f;
  for (int n = 0; n < 48; ++n) { s += psum[c * 48 + n]; q += pssq[c * 48 + n]; }
  float mean = s * (1.f / 196608.f);
  float var = q * (1.f / 196608.f) - mean * mean;
  float Aa = bng[c] * rsqrtf(var + EPS_BN);
  AB[c] = Aa;
  AB[9 + c] = bnb[c] - Aa * mean;
}

// ---------------------------------------------------------------------------
// Kernel F7: BARRIER-FREE, LDS-FREE streaming upsample+BN+residual.
// One f4 output per thread; g = linear f4 index (vol/out layout).
// Each lane computes its own zy-interp value from 4 cached h2 scalars
// (coalesced within the 16-lane group); x-neighbors come via __shfl inside
// the group. Values bitwise-identical to the old plane[] path. Structure is
// identical to the 6.9 TB/s fill: full occupancy, zero barriers, zero LDS.
// ---------------------------------------------------------------------------
__global__ __launch_bounds__(256) void kF7(
    const float* __restrict__ vol, const float* __restrict__ h2,
    const float* __restrict__ AB, const float* __restrict__ scp,
    float* __restrict__ outp)
{
  const int g = blockIdx.x * 256 + threadIdx.x;   // f4 index, < 28311552
  const int x = g & 15;
  const int oh = (g >> 4) & 63;
  const int od = (g >> 10) & 63;
  const int nc = g >> 16;                          // (n*9+c), 0..431

  const float* hb = h2 + (size_t)nc * 4096;
  int z0, z1, y0, y1; float fz, fy;
  axis16(od, z0, z1, fz);
  axis16(oh, y0, y1, fy);
  float w00 = (1.f - fz) * (1.f - fy), w01 = (1.f - fz) * fy;
  float w10 = fz * (1.f - fy), w11 = fz * fy;
  float zyv = w00 * hb[z0 * 256 + y0 * 16 + x] + w01 * hb[z0 * 256 + y1 * 16 + x]
            + w10 * hb[z1 * 256 + y0 * 16 + x] + w11 * hb[z1 * 256 + y1 * 16 + x];

  const int lane = threadIdx.x & 63;
  const int gb = lane & 48;                        // 16-lane group base
  float A = __shfl(zyv, gb | (x ? x - 1 : 0));
  float C = __shfl(zyv, gb | (x < 15 ? x + 1 : 15));
  float B = zyv;

  const int c = nc % 9;
  const float Aa = AB[c], Bb = AB[9 + c], sc = scp[0];

  f4 vv = ((const f4*)vol)[g];
  f4 oo;
  oo.x = vv.x + sc * fmaf(Aa, A + 0.625f * (B - A), Bb);
  oo.y = vv.y + sc * fmaf(Aa, A + 0.875f * (B - A), Bb);
  oo.z = vv.z + sc * fmaf(Aa, B + 0.125f * (C - B), Bb);
  oo.w = vv.w + sc * fmaf(Aa, B + 0.375f * (C - B), Bb);
  ((f4*)outp)[g] = oo;
}

// ---------------------------------------------------------------------------
extern "C" void kernel_launch(void* const* d_in, const int* in_sizes, int n_in,
                              void* d_out, int out_size, void* d_ws, size_t ws_size,
                              hipStream_t stream) {
  (void)in_sizes; (void)n_in; (void)out_size; (void)ws_size;
  const float* obj  = (const float*)d_in[0];
  const int*   eidx = (const int*)d_in[1];
  const float* vol  = (const float*)d_in[2];
  const float* W1   = (const float*)d_in[3];
  const float* as1  = (const float*)d_in[4];
  const float* ad1  = (const float*)d_in[5];
  const float* b1   = (const float*)d_in[6];
  const float* W2   = (const float*)d_in[7];
  const float* as2  = (const float*)d_in[8];
  const float* ad2  = (const float*)d_in[9];
  const float* b2   = (const float*)d_in[10];
  const float* lng  = (const float*)d_in[11];
  const float* lnb  = (const float*)d_in[12];
  const float* scp  = (const float*)d_in[13];
  const float* linW = (const float*)d_in[14];
  const float* linb = (const float*)d_in[15];
  const float* ct1W = (const float*)d_in[16];
  const float* ct1b = (const float*)d_in[17];
  const float* ct2W = (const float*)d_in[18];
  const float* ct2b = (const float*)d_in[19];
  const float* bng  = (const float*)d_in[20];
  const float* bnb  = (const float*)d_in[21];

  float* ws   = (float*)d_ws;
  float* xlg  = ws;                  // 432 f
  float* hct1 = ws + 432;            // 393216 f
  float* h2   = ws + 393648;         // 1769472 f
  float* psum = ws + 2163120;        // 432 f
  float* pssq = ws + 2163552;        // 432 f
  float* AB   = ws + 2163984;        // 18 f  (~8.66 MB total)

  float* out = (float*)d_out;

  kA2<<<1, 512, 0, stream>>>(obj, eidx, W1, as1, ad1, b1, W2, as2, ad2, b2,
                             lng, lnb, xlg);
  kBC<<<dim3(16, 48), 256, 0, stream>>>(xlg, linW, linb, ct1W, ct1b, hct1);
  kD<<<dim3(9, 48), 256, 0, stream>>>(hct1, ct2W, ct2b, h2, psum, pssq);
  kE2<<<1, 64, 0, stream>>>(psum, pssq, bng, bnb, AB);
  kF7<<<110592, 256, 0, stream>>>(vol, h2, AB, scp, out);
}